// Round 11
// baseline (2292.563 us; speedup 1.0000x reference)
//
#include <hip/hip_runtime.h>
#include <math.h>

#define NPTS 2048
#define NB 8
#define R 2        // rows per thread
#define NW 16      // waves per block = column chunks
#define BROWS 128  // rows per block
#define CPAIR 64   // col-pairs per wave chunk (128 cols)

typedef float v2f __attribute__((ext_vector_type(2)));

__device__ __forceinline__ float wexp2(float v) { return __builtin_amdgcn_exp2f(v); }
__device__ __forceinline__ v2f fma2(v2f a, v2f b, v2f c) {
  return __builtin_elementwise_fma(a, b, c);
}
__device__ __forceinline__ v2f max2(v2f a, v2f b) {
  return __builtin_elementwise_max(a, b);
}

// ---------------------------------------------------------------------------
// init: packed point records (x,y,z, 0.5*|p|^2), zero potentials, zero output.
// ---------------------------------------------------------------------------
__global__ __launch_bounds__(256) void emd_init(const float* __restrict__ x,
                                                const float* __restrict__ y,
                                                float4* __restrict__ x4,
                                                float4* __restrict__ y4,
                                                float* __restrict__ pot0,
                                                float* __restrict__ out) {
  int t = blockIdx.x * blockDim.x + threadIdx.x;  // 0..65535
  if (t < NB * NPTS) {
    float a0 = x[3 * t], a1 = x[3 * t + 1], a2 = x[3 * t + 2];
    x4[t] = make_float4(a0, a1, a2, 0.5f * (a0 * a0 + a1 * a1 + a2 * a2));
    float b0 = y[3 * t], b1 = y[3 * t + 1], b2 = y[3 * t + 2];
    y4[t] = make_float4(b0, b1, b2, 0.5f * (b0 * b0 + b1 * b1 + b2 * b2));
  }
  pot0[t] = 0.0f;
  if (t == 0) out[0] = 0.0f;
}

// ---------------------------------------------------------------------------
// Geometry (both sweeps): 512 blocks x 1024 threads; block=(mat,b,128-row
// group); 16 waves = column chunks of 128 cols (64 pairs); R=2 rows/thread;
// 2 blocks/CU -> 8 waves/SIMD. Col pair packed A=(x0,x1,y0,y1),
// B=(z0,z1,w0,w1), w=(h-0.5|y|^2)*c.
// ---------------------------------------------------------------------------

// Bootstrap sweep: exact online softmax (first eps only) + amax store.
__global__ __launch_bounds__(1024, 8) void emd_sweep_boot(
    const float4* __restrict__ x4, const float4* __restrict__ y4,
    const float* __restrict__ pot_in, float* __restrict__ pot_out,
    float* __restrict__ amax_out, float c, float neg_eps_ln2, float eps_logM) {
  __shared__ union {
    struct {
      float4 A[NPTS / 2];
      float4 B[NPTS / 2];
    } cp;
    struct {
      float m[NW][BROWS];
      float l[NW][BROWS];
    } mg;
  } sh;

  int blk = blockIdx.x;            // 0..511
  int mat = blk >> 7;
  int b = (blk >> 4) & 7;
  int rg = blk & 15;               // 128-row group
  int tid = threadIdx.x;
  int lane = tid & 63;
  int w = tid >> 6;                // 0..15

  const float4* rowp = (mat == 1 || mat == 3) ? y4 : x4;
  const float4* colp = (mat == 0 || mat == 3) ? y4 : x4;
  int hidx = (mat < 2) ? (mat ^ 1) : mat;
  const float* h = pot_in + (hidx * NB + b) * NPTS;
  const float4* colb = colp + b * NPTS;

  {
    float4 q0 = colb[2 * tid];
    float4 q1 = colb[2 * tid + 1];
    float2 hv = ((const float2*)h)[tid];
    sh.cp.A[tid] = make_float4(q0.x, q1.x, q0.y, q1.y);
    sh.cp.B[tid] = make_float4(q0.z, q1.z, (hv.x - q0.w) * c, (hv.y - q1.w) * c);
  }
  __syncthreads();

  int rowbase = rg * BROWS;
  const float4* rowb = rowp + b * NPTS + rowbase;

  v2f xs0[R], xs1[R], xs2[R];
  float m[R], l[R];
#pragma unroll
  for (int r = 0; r < R; ++r) {
    float4 p = rowb[r * 64 + lane];
    float a0 = p.x * c, a1 = p.y * c, a2 = p.z * c;
    xs0[r] = (v2f){a0, a0};
    xs1[r] = (v2f){a1, a1};
    xs2[r] = (v2f){a2, a2};
    m[r] = -INFINITY;
    l[r] = 0.0f;
  }

  int p0 = w * CPAIR;
  for (int tp = 0; tp < CPAIR; tp += 4) {
    float4 A[4], B[4];
#pragma unroll
    for (int j = 0; j < 4; ++j) {
      A[j] = sh.cp.A[p0 + tp + j];
      B[j] = sh.cp.B[p0 + tp + j];
    }
#pragma unroll
    for (int r = 0; r < R; ++r) {
      v2f s2[4];
#pragma unroll
      for (int j = 0; j < 4; ++j) {
        v2f qx = {A[j].x, A[j].y};
        v2f qy = {A[j].z, A[j].w};
        v2f qz = {B[j].x, B[j].y};
        v2f qw = {B[j].z, B[j].w};
        s2[j] = fma2(xs0[r], qx, fma2(xs1[r], qy, fma2(xs2[r], qz, qw)));
      }
      v2f t0 = max2(s2[0], s2[1]);
      v2f t1 = max2(s2[2], s2[3]);
      v2f u = max2(t0, t1);
      float mt = fmaxf(u.x, u.y);
      float mn = fmaxf(m[r], mt);
      v2f mn2 = {mn, mn};
      v2f acc = {0.0f, 0.0f};
#pragma unroll
      for (int j = 0; j < 4; ++j) {
        v2f d = s2[j] - mn2;
        v2f e;
        e.x = wexp2(d.x);
        e.y = wexp2(d.y);
        acc += e;
      }
      float er = wexp2(m[r] - mn);
      l[r] = fmaf(l[r], er, acc.x + acc.y);
      m[r] = mn;
    }
  }

  __syncthreads();
#pragma unroll
  for (int r = 0; r < R; ++r) {
    sh.mg.m[w][r * 64 + lane] = m[r];
    sh.mg.l[w][r * 64 + lane] = l[r];
  }
  __syncthreads();

  if (w < 2) {
    int row = w * 64 + lane;       // 0..127
    float M = sh.mg.m[0][row];
#pragma unroll
    for (int q = 1; q < NW; ++q) M = fmaxf(M, sh.mg.m[q][row]);
    float L = 0.0f;
#pragma unroll
    for (int q = 0; q < NW; ++q)
      L += sh.mg.l[q][row] * wexp2(sh.mg.m[q][row] - M);
    float pw = rowb[row].w;
    float res = pw + neg_eps_ln2 * (M + log2f(L)) + eps_logM;
    float invc = -neg_eps_ln2;     // = 1/c
    amax_out[(mat * NB + b) * NPTS + rowbase + row] = M * invc;
    const float* oldp = pot_in + (mat * NB + b) * NPTS + rowbase;
    float* outp = pot_out + (mat * NB + b) * NPTS + rowbase;
    outp[row] = 0.5f * (oldp[row] + res);
  }
}

// ---------------------------------------------------------------------------
// Fixed-reference sweep with PACKED POLY exp2 (no v_exp_f32 in inner loop):
//   d = clamp(s - Mref, -46, .)          (pk_sub, pk_max)
//   t = d + 1.5*2^23 (RNE magic round)   (pk_add)   n = t - MAGIC  r = d - n
//   p = deg-5 Taylor 2^r on [-.5,.5]     (5 pk_fma, rel err ~2.4e-6)
//   e = bitcast( (t_bits<<23) + p_bits ) (v_lshl_add_u32: exact *2^n)
// All pk ops issue at 2 cyc vs v_exp_f32 ~16 cyc -> ~24% issue-cycle cut.
// Clamp keeps exponents valid; spurious mass <= 2048*2^-46 (rel <2^-21).
// ---------------------------------------------------------------------------
template <bool FINAL>
__global__ __launch_bounds__(1024, 8) void emd_sweep_ref(
    const float4* __restrict__ x4, const float4* __restrict__ y4,
    const float* __restrict__ pot_in, float* __restrict__ pot_out,
    const float* __restrict__ amax_in, float* __restrict__ amax_out,
    float* __restrict__ out, float c, float neg_eps_ln2, float eps_logM) {
  __shared__ union {
    struct {
      float4 A[NPTS / 2];          // 16 KB
      float4 B[NPTS / 2];          // 16 KB
    } cp;
    float lbuf[NW][BROWS];         // merge phase (colpack dead)
  } sh;

  int blk = blockIdx.x;            // 0..511
  int mat = blk >> 7;
  int b = (blk >> 4) & 7;
  int rg = blk & 15;
  int tid = threadIdx.x;
  int lane = tid & 63;
  int w = tid >> 6;

  const float4* rowp = (mat == 1 || mat == 3) ? y4 : x4;
  const float4* colp = (mat == 0 || mat == 3) ? y4 : x4;
  int hidx = (mat < 2) ? (mat ^ 1) : mat;
  const float* h = pot_in + (hidx * NB + b) * NPTS;
  const float4* colb = colp + b * NPTS;

  {
    float4 q0 = colb[2 * tid];
    float4 q1 = colb[2 * tid + 1];
    float2 hv = ((const float2*)h)[tid];
    sh.cp.A[tid] = make_float4(q0.x, q1.x, q0.y, q1.y);
    sh.cp.B[tid] = make_float4(q0.z, q1.z, (hv.x - q0.w) * c, (hv.y - q1.w) * c);
  }

  int rowbase = rg * BROWS;
  const float4* rowb = rowp + b * NPTS + rowbase;
  const float* amrow = amax_in + (mat * NB + b) * NPTS + rowbase;

  v2f xs0[R], xs1[R], xs2[R], mref2[R], acc[R];
#pragma unroll
  for (int r = 0; r < R; ++r) {
    float4 p = rowb[r * 64 + lane];
    float a0 = p.x * c, a1 = p.y * c, a2 = p.z * c;
    xs0[r] = (v2f){a0, a0};
    xs1[r] = (v2f){a1, a1};
    xs2[r] = (v2f){a2, a2};
    float mr = amrow[r * 64 + lane] * c;
    mref2[r] = (v2f){mr, mr};
    acc[r] = (v2f){0.0f, 0.0f};
  }
  __syncthreads();

  const v2f MAGIC = {12582912.0f, 12582912.0f};  // 1.5 * 2^23
  const v2f CLMP = {-46.0f, -46.0f};
  const v2f C0 = {1.0f, 1.0f};
  const v2f C1 = {0.69314718056f, 0.69314718056f};
  const v2f C2 = {0.24022650696f, 0.24022650696f};
  const v2f C3 = {0.05550410866f, 0.05550410866f};
  const v2f C4 = {0.00961812911f, 0.00961812911f};
  const v2f C5 = {0.00133335581f, 0.00133335581f};

  int p0 = w * CPAIR;
  for (int tp = 0; tp < CPAIR; tp += 4) {   // 4 pairs = 8 cols per iter
    float4 A[4], B[4];
#pragma unroll
    for (int j = 0; j < 4; ++j) {
      A[j] = sh.cp.A[p0 + tp + j];
      B[j] = sh.cp.B[p0 + tp + j];
    }
#pragma unroll
    for (int r = 0; r < R; ++r) {
#pragma unroll
      for (int j = 0; j < 4; ++j) {
        v2f qx = {A[j].x, A[j].y};
        v2f qy = {A[j].z, A[j].w};
        v2f qz = {B[j].x, B[j].y};
        v2f qw = {B[j].z, B[j].w};
        v2f s2 = fma2(xs0[r], qx, fma2(xs1[r], qy, fma2(xs2[r], qz, qw)));
        v2f d = max2(s2 - mref2[r], CLMP);
        v2f t = d + MAGIC;     // RNE -> n in t's mantissa
        v2f n = t - MAGIC;     // exact float n
        v2f rr = d - n;        // r in [-0.5, 0.5]
        v2f p = fma2(rr, fma2(rr, fma2(rr, fma2(rr, fma2(rr, C5, C4), C3), C2), C1), C0);
        int e0 = (__float_as_int(t.x) << 23) + __float_as_int(p.x);
        int e1 = (__float_as_int(t.y) << 23) + __float_as_int(p.y);
        v2f e = {__int_as_float(e0), __int_as_float(e1)};
        acc[r] += e;
      }
    }
  }

  __syncthreads();  // colpack dead; safe to overwrite (union)
#pragma unroll
  for (int r = 0; r < R; ++r)
    sh.lbuf[w][r * 64 + lane] = acc[r].x + acc[r].y;
  __syncthreads();

  if (w < 2) {
    int row = w * 64 + lane;       // 0..127
    float L = sh.lbuf[0][row];
#pragma unroll
    for (int q = 1; q < NW; ++q) L += sh.lbuf[q][row];
    float mr = amrow[row] * c;
    float lse = mr + log2f(L);
    float pw = rowb[row].w;
    float res = pw + neg_eps_ln2 * lse + eps_logM;
    float invc = -neg_eps_ln2;
    if (FINAL) {
      float sign = (mat < 2) ? 1.0f : -1.0f;
      float val = sign * res * (1.0f / (float)(NB * NPTS));
#pragma unroll
      for (int off = 32; off; off >>= 1) val += __shfl_xor(val, off);
      if (lane == 0) atomicAdd(out, val);
    } else {
      amax_out[(mat * NB + b) * NPTS + rowbase + row] = lse * invc;
      const float* oldp = pot_in + (mat * NB + b) * NPTS + rowbase;
      float* outp = pot_out + (mat * NB + b) * NPTS + rowbase;
      outp[row] = 0.5f * (oldp[row] + res);
    }
  }
}

// ---------------------------------------------------------------------------
extern "C" void kernel_launch(void* const* d_in, const int* in_sizes, int n_in,
                              void* d_out, int out_size, void* d_ws, size_t ws_size,
                              hipStream_t stream) {
  const float* x = (const float*)d_in[0];
  const float* y = (const float*)d_in[1];
  float* out = (float*)d_out;

  char* ws = (char*)d_ws;
  float4* x4 = (float4*)ws;                        // 256 KB
  float4* y4 = (float4*)(ws + 262144);             // 256 KB
  float* pot = (float*)(ws + 524288);              // 2 * 65536 floats = 512 KB
  float* amax = (float*)(ws + 1048576);            // 65536 floats = 256 KB

  emd_init<<<256, 256, 0, stream>>>(x, y, x4, y4, pot, out);

  // eps schedule: s=8.0, *=0.9 while s>0.01; eps = f32(s)^2; append 0.01^2
  float eps_arr[80];
  int ne = 0;
  double s = 8.0;
  while (s > 0.01) {
    float sf = (float)s;
    eps_arr[ne++] = sf * sf;
    s *= 0.9;
  }
  {
    float bf = 0.01f;
    eps_arr[ne++] = bf * bf;
  }

  const double LOG2E = 1.4426950408889634;
  const double LN2 = 0.6931471805599453;
  const double LOG2048 = 7.624618986159398;

  int cur = 0;
  for (int k = 0; k < ne; ++k) {
    float eps = eps_arr[k];
    float c = (float)(LOG2E / (double)eps);
    float nel = (float)(-(double)eps * LN2);
    float elM = (float)((double)eps * LOG2048);
    if (k == 0) {
      emd_sweep_boot<<<512, 1024, 0, stream>>>(x4, y4, pot + cur * 65536,
                                               pot + (1 - cur) * 65536, amax,
                                               c, nel, elM);
    } else {
      emd_sweep_ref<false><<<512, 1024, 0, stream>>>(
          x4, y4, pot + cur * 65536, pot + (1 - cur) * 65536, amax, amax, out,
          c, nel, elM);
    }
    cur ^= 1;
  }

  {
    float eps = eps_arr[ne - 1];
    float c = (float)(LOG2E / (double)eps);
    float nel = (float)(-(double)eps * LN2);
    float elM = (float)((double)eps * LOG2048);
    emd_sweep_ref<true><<<512, 1024, 0, stream>>>(
        x4, y4, pot + cur * 65536, nullptr, amax, nullptr, out, c, nel, elM);
  }
}

// Round 14
// 1574.184 us; speedup vs baseline: 1.4564x; 1.4564x over previous
//
#include <hip/hip_runtime.h>
#include <math.h>

#define NPTS 2048
#define NB 8

typedef float v2f __attribute__((ext_vector_type(2)));

__device__ __forceinline__ float wexp2(float v) { return __builtin_amdgcn_exp2f(v); }
__device__ __forceinline__ v2f fma2(v2f a, v2f b, v2f c) {
  return __builtin_elementwise_fma(a, b, c);
}
__device__ __forceinline__ v2f max2(v2f a, v2f b) {
  return __builtin_elementwise_max(a, b);
}

// ---------------------------------------------------------------------------
// init: packed records (x,y,z, 0.5|p|^2); zero pot buffer 0; zero out.
// ---------------------------------------------------------------------------
__global__ __launch_bounds__(256) void emd_init(const float* __restrict__ x,
                                                const float* __restrict__ y,
                                                float4* __restrict__ x4,
                                                float4* __restrict__ y4,
                                                float* __restrict__ pot0,
                                                float* __restrict__ out) {
  int t = blockIdx.x * blockDim.x + threadIdx.x;  // 0..65535
  if (t < NB * NPTS) {
    float a0 = x[3 * t], a1 = x[3 * t + 1], a2 = x[3 * t + 2];
    x4[t] = make_float4(a0, a1, a2, 0.5f * (a0 * a0 + a1 * a1 + a2 * a2));
    float b0 = y[3 * t], b1 = y[3 * t + 1], b2 = y[3 * t + 2];
    y4[t] = make_float4(b0, b1, b2, 0.5f * (b0 * b0 + b1 * b1 + b2 * b2));
  }
  pot0[t] = 0.0f;
  if (t == 0) out[0] = 0.0f;
}

// ---------------------------------------------------------------------------
// Boot sweep — the VALIDATED R10 kernel (exact online softmax), iteration 1.
// 512 blocks x 1024 thr, block=(mat,b,128-row grp), 16 waves = 128-col
// chunks, R=2. Writes pot_out = 0.5*(old+res) and amax_out = M/c (v+pw
// units), the reference for the next sweep's rows.
// ---------------------------------------------------------------------------
__global__ __launch_bounds__(1024, 8) void emd_sweep_boot(
    const float4* __restrict__ x4, const float4* __restrict__ y4,
    const float* __restrict__ pot_in, float* __restrict__ pot_out,
    float* __restrict__ amax_out, float c, float neg_eps_ln2, float eps_logM) {
  __shared__ union {
    struct { float4 A[NPTS / 2]; float4 B[NPTS / 2]; } cp;
    struct { float m[16][128]; float l[16][128]; } mg;
  } sh;

  int blk = blockIdx.x;
  int mat = blk >> 7;
  int b = (blk >> 4) & 7;
  int rg = blk & 15;
  int tid = threadIdx.x;
  int lane = tid & 63;
  int w = tid >> 6;

  const float4* rowp = (mat & 1) ? y4 : x4;
  const float4* colp = (mat == 0 || mat == 3) ? y4 : x4;
  int hidx = (mat < 2) ? (mat ^ 1) : mat;
  const float* h = pot_in + (hidx * NB + b) * NPTS;
  const float4* colb = colp + b * NPTS;

  {
    float4 q0 = colb[2 * tid];
    float4 q1 = colb[2 * tid + 1];
    float2 hv = ((const float2*)h)[tid];
    sh.cp.A[tid] = make_float4(q0.x, q1.x, q0.y, q1.y);
    sh.cp.B[tid] = make_float4(q0.z, q1.z, (hv.x - q0.w) * c, (hv.y - q1.w) * c);
  }
  __syncthreads();

  int rowbase = rg * 128;
  const float4* rowb = rowp + b * NPTS + rowbase;

  v2f xs0[2], xs1[2], xs2[2];
  float m[2], l[2];
#pragma unroll
  for (int r = 0; r < 2; ++r) {
    float4 p = rowb[r * 64 + lane];
    float a0 = p.x * c, a1 = p.y * c, a2 = p.z * c;
    xs0[r] = (v2f){a0, a0};
    xs1[r] = (v2f){a1, a1};
    xs2[r] = (v2f){a2, a2};
    m[r] = -INFINITY;
    l[r] = 0.0f;
  }

  int p0 = w * 64;
  for (int tp = 0; tp < 64; tp += 4) {
    float4 A[4], B[4];
#pragma unroll
    for (int j = 0; j < 4; ++j) {
      A[j] = sh.cp.A[p0 + tp + j];
      B[j] = sh.cp.B[p0 + tp + j];
    }
#pragma unroll
    for (int r = 0; r < 2; ++r) {
      v2f s2[4];
#pragma unroll
      for (int j = 0; j < 4; ++j) {
        v2f qx = {A[j].x, A[j].y};
        v2f qy = {A[j].z, A[j].w};
        v2f qz = {B[j].x, B[j].y};
        v2f qw = {B[j].z, B[j].w};
        s2[j] = fma2(xs0[r], qx, fma2(xs1[r], qy, fma2(xs2[r], qz, qw)));
      }
      v2f t0 = max2(s2[0], s2[1]);
      v2f t1 = max2(s2[2], s2[3]);
      v2f u = max2(t0, t1);
      float mt = fmaxf(u.x, u.y);
      float mn = fmaxf(m[r], mt);
      v2f mn2 = {mn, mn};
      v2f acc = {0.0f, 0.0f};
#pragma unroll
      for (int j = 0; j < 4; ++j) {
        v2f d = s2[j] - mn2;
        v2f e;
        e.x = wexp2(d.x);
        e.y = wexp2(d.y);
        acc += e;
      }
      l[r] = fmaf(l[r], wexp2(m[r] - mn), acc.x + acc.y);
      m[r] = mn;
    }
  }

  __syncthreads();
#pragma unroll
  for (int r = 0; r < 2; ++r) {
    sh.mg.m[w][r * 64 + lane] = m[r];
    sh.mg.l[w][r * 64 + lane] = l[r];
  }
  __syncthreads();

  if (w < 2) {
    int row = w * 64 + lane;  // 0..127
    float M = sh.mg.m[0][row];
#pragma unroll
    for (int q = 1; q < 16; ++q) M = fmaxf(M, sh.mg.m[q][row]);
    float L = 0.0f;
#pragma unroll
    for (int q = 0; q < 16; ++q)
      L += sh.mg.l[q][row] * wexp2(sh.mg.m[q][row] - M);
    float pw = rowb[row].w;
    float res = pw + neg_eps_ln2 * (M + log2f(L)) + eps_logM;
    float invc = -neg_eps_ln2;  // = 1/c
    int idx = (mat * NB + b) * NPTS + rowbase + row;
    amax_out[idx] = M * invc;
    pot_out[idx] = 0.5f * (pot_in[idx] + res);
  }
}

// ---------------------------------------------------------------------------
// Partial sweep: fixed-reference exp accumulate over a 1024-col half.
// 512 blocks x 1024 thr; block=(mat(2b), b(3b), rg(3b): 256-row grp,
// cg(1b): col half). 16 waves = 64-col chunks of this half; R=4 rows/thread
// -> 2048 ds_read_b128/CU (half of R10). Reads fully-updated pot_in (merge
// ran before). Writes the half's partial row sums L to Lp.
// ---------------------------------------------------------------------------
__global__ __launch_bounds__(1024, 8) void emd_partial(
    const float4* __restrict__ x4, const float4* __restrict__ y4,
    const float* __restrict__ pot_in, const float* __restrict__ am_in,
    float* __restrict__ Lp, float c) {
  __shared__ union {
    struct { float4 A[512]; float4 B[512]; } cp;  // 16 KB (this col half)
    float lbuf[16][256];                          // 16 KB (merge phase)
  } sh;

  int blk = blockIdx.x;  // mat(2) | b(3) | rg(3) | cg(1)
  int mat = blk >> 7;
  int b = (blk >> 4) & 7;
  int rg = (blk >> 1) & 7;
  int cg = blk & 1;
  int tid = threadIdx.x;
  int lane = tid & 63;
  int w = tid >> 6;

  const float4* rowp = (mat & 1) ? y4 : x4;
  const float4* colp = (mat == 0 || mat == 3) ? y4 : x4;
  int hidx = (mat < 2) ? (mat ^ 1) : mat;
  const float* h = pot_in + (hidx * NB + b) * NPTS;
  const float4* colb = colp + b * NPTS;

  if (tid < 512) {
    int jg = cg * 1024 + 2 * tid;
    float4 q0 = colb[jg];
    float4 q1 = colb[jg + 1];
    float2 hv = *(const float2*)(h + jg);
    sh.cp.A[tid] = make_float4(q0.x, q1.x, q0.y, q1.y);
    sh.cp.B[tid] = make_float4(q0.z, q1.z, (hv.x - q0.w) * c, (hv.y - q1.w) * c);
  }
  __syncthreads();

  int rowbase = rg * 256;
  const float4* rowb = rowp + b * NPTS + rowbase;
  const float* amrow = am_in + (mat * NB + b) * NPTS + rowbase;

  v2f xs0[4], xs1[4], xs2[4], mref2[4], acc[4];
#pragma unroll
  for (int r = 0; r < 4; ++r) {
    float4 p = rowb[r * 64 + lane];
    float a0 = p.x * c, a1 = p.y * c, a2 = p.z * c;
    xs0[r] = (v2f){a0, a0};
    xs1[r] = (v2f){a1, a1};
    xs2[r] = (v2f){a2, a2};
    float mr = amrow[r * 64 + lane] * c;  // reference (v+pw units) rescaled
    mref2[r] = (v2f){mr, mr};
    acc[r] = (v2f){0.0f, 0.0f};
  }

  int p0 = w * 32;  // 32 pairs (64 cols) per wave
  for (int tp = 0; tp < 32; ++tp) {
    float4 A = sh.cp.A[p0 + tp];
    float4 B = sh.cp.B[p0 + tp];
    v2f qx = {A.x, A.y};
    v2f qy = {A.z, A.w};
    v2f qz = {B.x, B.y};
    v2f qw = {B.z, B.w};
#pragma unroll
    for (int r = 0; r < 4; ++r) {
      v2f s2 = fma2(xs0[r], qx, fma2(xs1[r], qy, fma2(xs2[r], qz, qw)));
      v2f d = s2 - mref2[r];
      v2f e;
      e.x = wexp2(d.x);
      e.y = wexp2(d.y);
      acc[r] += e;
    }
  }

  __syncthreads();  // colpack dead; safe to overwrite (union)
#pragma unroll
  for (int r = 0; r < 4; ++r)
    sh.lbuf[w][r * 64 + lane] = acc[r].x + acc[r].y;
  __syncthreads();

  if (w < 4) {
    int row = w * 64 + lane;  // 0..255
    float L = sh.lbuf[0][row];
#pragma unroll
    for (int q = 1; q < 16; ++q) L += sh.lbuf[q][row];
    Lp[2 * ((mat * NB + b) * NPTS) + cg * NPTS + rowbase + row] = L;
  }
}

// ---------------------------------------------------------------------------
// Merge: sum the two column-half partials, finish the softmin, update the
// potential and write the next rows-reference (lse, v+pw units). FINAL:
// signed mean into out. NB: normalization is 1/(NB*NPTS) = 1/16384 — the
// R12/R13 bug was 1/65536 here (output exactly 1/4 of correct).
// ---------------------------------------------------------------------------
template <bool FINAL>
__global__ __launch_bounds__(256) void emd_merge(
    const float4* __restrict__ x4, const float4* __restrict__ y4,
    const float* __restrict__ Lp, const float* __restrict__ am_in,
    const float* __restrict__ pot_in, float* __restrict__ pot_out,
    float* __restrict__ am_out, float* __restrict__ out,
    float invc, float elM) {
  int t = blockIdx.x * 256 + threadIdx.x;  // 0..65535
  int mat = t >> 14;
  int b = (t >> 11) & 7;
  int i = t & 2047;
  const float4* rowp = (mat & 1) ? y4 : x4;
  float pw = rowp[b * NPTS + i].w;
  int base = (mat * NB + b) * NPTS;
  float L = Lp[2 * base + i] + Lp[2 * base + NPTS + i];
  float lse = fmaf(log2f(L), invc, am_in[base + i]);  // v+pw units
  float res = pw - lse + elM;
  if (FINAL) {
    float sign = (mat < 2) ? 1.0f : -1.0f;
    float val = sign * res * (1.0f / (float)(NB * NPTS));  // 1/16384
#pragma unroll
    for (int off = 32; off; off >>= 1) val += __shfl_xor(val, off);
    if ((threadIdx.x & 63) == 0) atomicAdd(out, val);
  } else {
    pot_out[base + i] = 0.5f * (pot_in[base + i] + res);
    am_out[base + i] = lse;
  }
}

// ---------------------------------------------------------------------------
extern "C" void kernel_launch(void* const* d_in, const int* in_sizes, int n_in,
                              void* d_out, int out_size, void* d_ws, size_t ws_size,
                              hipStream_t stream) {
  const float* x = (const float*)d_in[0];
  const float* y = (const float*)d_in[1];
  float* out = (float*)d_out;

  char* ws = (char*)d_ws;
  float4* x4 = (float4*)ws;                          // 256 KB
  float4* y4 = (float4*)(ws + 262144);               // 256 KB
  float* pot = (float*)(ws + 524288);                // 2 x 65536 f = 512 KB
  float* am[2];
  am[0] = (float*)(ws + 1048576);                    // 256 KB
  am[1] = (float*)(ws + 1310720);                    // 256 KB
  float* Lp = (float*)(ws + 1572864);                // 131072 f = 512 KB

  emd_init<<<256, 256, 0, stream>>>(x, y, x4, y4, pot, out);

  // eps schedule: s=8.0, *=0.9 while s>0.01; eps=f32(s)^2; append 0.01^2
  float eps_arr[80];
  int ne = 0;
  double s = 8.0;
  while (s > 0.01) {
    float sf = (float)s;
    eps_arr[ne++] = sf * sf;
    s *= 0.9;
  }
  {
    float bf = 0.01f;
    eps_arr[ne++] = bf * bf;
  }

  const double LOG2E = 1.4426950408889634;
  const double LN2 = 0.6931471805599453;
  const double LOG2048 = 7.624618986159398;

  // iteration 1 (boot): pot0 (zeroed) -> pot1, writes am[0]
  {
    float eps = eps_arr[0];
    float c = (float)(LOG2E / (double)eps);
    float nel = (float)(-(double)eps * LN2);
    float elM = (float)((double)eps * LOG2048);
    emd_sweep_boot<<<512, 1024, 0, stream>>>(x4, y4, pot, pot + 65536,
                                             am[0], c, nel, elM);
  }

  // iterations 2..ne: sweep k = partial + merge, eps = eps_arr[k]
  for (int k = 1; k < ne; ++k) {
    float eps = eps_arr[k];
    float c = (float)(LOG2E / (double)eps);
    float invc = (float)((double)eps * LN2);
    float elM = (float)((double)eps * LOG2048);
    float* potIn = pot + (k % 2) * 65536;
    float* potOut = pot + ((k + 1) % 2) * 65536;
    const float* amIn = am[(k - 1) % 2];
    float* amOut = am[k % 2];
    emd_partial<<<512, 1024, 0, stream>>>(x4, y4, potIn, amIn, Lp, c);
    emd_merge<false><<<256, 256, 0, stream>>>(x4, y4, Lp, amIn, potIn, potOut,
                                              amOut, nullptr, invc, elM);
  }

  // final extrapolation at eps_t with the final potentials
  {
    float eps = eps_arr[ne - 1];
    float c = (float)(LOG2E / (double)eps);
    float invc = (float)((double)eps * LN2);
    float elM = (float)((double)eps * LOG2048);
    float* potIn = pot + (ne % 2) * 65536;
    const float* amIn = am[(ne - 1) % 2];
    emd_partial<<<512, 1024, 0, stream>>>(x4, y4, potIn, amIn, Lp, c);
    emd_merge<true><<<256, 256, 0, stream>>>(x4, y4, Lp, amIn, nullptr, nullptr,
                                             nullptr, out, invc, elM);
  }
}

// Round 15
// 1492.602 us; speedup vs baseline: 1.5360x; 1.0547x over previous
//
#include <hip/hip_runtime.h>
#include <math.h>

#define NPTS 2048
#define NB 8

typedef float v2f __attribute__((ext_vector_type(2)));

__device__ __forceinline__ float wexp2(float v) { return __builtin_amdgcn_exp2f(v); }
__device__ __forceinline__ v2f fma2(v2f a, v2f b, v2f c) {
  return __builtin_elementwise_fma(a, b, c);
}
__device__ __forceinline__ v2f max2(v2f a, v2f b) {
  return __builtin_elementwise_max(a, b);
}

// ---------------------------------------------------------------------------
// init: packed records (x,y,z, 0.5|p|^2); zero pot buffer 0; zero out.
// ---------------------------------------------------------------------------
__global__ __launch_bounds__(256) void emd_init(const float* __restrict__ x,
                                                const float* __restrict__ y,
                                                float4* __restrict__ x4,
                                                float4* __restrict__ y4,
                                                float* __restrict__ pot0,
                                                float* __restrict__ out) {
  int t = blockIdx.x * blockDim.x + threadIdx.x;  // 0..65535
  if (t < NB * NPTS) {
    float a0 = x[3 * t], a1 = x[3 * t + 1], a2 = x[3 * t + 2];
    x4[t] = make_float4(a0, a1, a2, 0.5f * (a0 * a0 + a1 * a1 + a2 * a2));
    float b0 = y[3 * t], b1 = y[3 * t + 1], b2 = y[3 * t + 2];
    y4[t] = make_float4(b0, b1, b2, 0.5f * (b0 * b0 + b1 * b1 + b2 * b2));
  }
  pot0[t] = 0.0f;
  if (t == 0) out[0] = 0.0f;
}

// ---------------------------------------------------------------------------
// Boot sweep (iteration 0, exact online softmax — validated R10 kernel).
// Writes pot_out = 0.5*(0+res), am0 = M_0/c (R_0: sweep-1 rows + sweep-2
// decode ref), am1 = lse_0/c (R_1: sweep-2 rows + sweep-3 decode ref).
// ---------------------------------------------------------------------------
__global__ __launch_bounds__(1024, 8) void emd_sweep_boot(
    const float4* __restrict__ x4, const float4* __restrict__ y4,
    const float* __restrict__ pot_in, float* __restrict__ pot_out,
    float* __restrict__ am0, float* __restrict__ am1,
    float c, float neg_eps_ln2, float eps_logM) {
  __shared__ union {
    struct { float4 A[NPTS / 2]; float4 B[NPTS / 2]; } cp;
    struct { float m[16][128]; float l[16][128]; } mg;
  } sh;

  int blk = blockIdx.x;
  int mat = blk >> 7;
  int b = (blk >> 4) & 7;
  int rg = blk & 15;
  int tid = threadIdx.x;
  int lane = tid & 63;
  int w = tid >> 6;

  const float4* rowp = (mat & 1) ? y4 : x4;
  const float4* colp = (mat == 0 || mat == 3) ? y4 : x4;
  int hidx = (mat < 2) ? (mat ^ 1) : mat;
  const float* h = pot_in + (hidx * NB + b) * NPTS;
  const float4* colb = colp + b * NPTS;

  {
    float4 q0 = colb[2 * tid];
    float4 q1 = colb[2 * tid + 1];
    float2 hv = ((const float2*)h)[tid];
    sh.cp.A[tid] = make_float4(q0.x, q1.x, q0.y, q1.y);
    sh.cp.B[tid] = make_float4(q0.z, q1.z, (hv.x - q0.w) * c, (hv.y - q1.w) * c);
  }
  __syncthreads();

  int rowbase = rg * 128;
  const float4* rowb = rowp + b * NPTS + rowbase;

  v2f xs0[2], xs1[2], xs2[2];
  float m[2], l[2];
#pragma unroll
  for (int r = 0; r < 2; ++r) {
    float4 p = rowb[r * 64 + lane];
    float a0 = p.x * c, a1 = p.y * c, a2 = p.z * c;
    xs0[r] = (v2f){a0, a0};
    xs1[r] = (v2f){a1, a1};
    xs2[r] = (v2f){a2, a2};
    m[r] = -INFINITY;
    l[r] = 0.0f;
  }

  int p0 = w * 64;
  for (int tp = 0; tp < 64; tp += 4) {
    float4 A[4], B[4];
#pragma unroll
    for (int j = 0; j < 4; ++j) {
      A[j] = sh.cp.A[p0 + tp + j];
      B[j] = sh.cp.B[p0 + tp + j];
    }
#pragma unroll
    for (int r = 0; r < 2; ++r) {
      v2f s2[4];
#pragma unroll
      for (int j = 0; j < 4; ++j) {
        v2f qx = {A[j].x, A[j].y};
        v2f qy = {A[j].z, A[j].w};
        v2f qz = {B[j].x, B[j].y};
        v2f qw = {B[j].z, B[j].w};
        s2[j] = fma2(xs0[r], qx, fma2(xs1[r], qy, fma2(xs2[r], qz, qw)));
      }
      v2f t0 = max2(s2[0], s2[1]);
      v2f t1 = max2(s2[2], s2[3]);
      v2f u = max2(t0, t1);
      float mt = fmaxf(u.x, u.y);
      float mn = fmaxf(m[r], mt);
      v2f mn2 = {mn, mn};
      v2f acc = {0.0f, 0.0f};
#pragma unroll
      for (int j = 0; j < 4; ++j) {
        v2f d = s2[j] - mn2;
        v2f e;
        e.x = wexp2(d.x);
        e.y = wexp2(d.y);
        acc += e;
      }
      l[r] = fmaf(l[r], wexp2(m[r] - mn), acc.x + acc.y);
      m[r] = mn;
    }
  }

  __syncthreads();
#pragma unroll
  for (int r = 0; r < 2; ++r) {
    sh.mg.m[w][r * 64 + lane] = m[r];
    sh.mg.l[w][r * 64 + lane] = l[r];
  }
  __syncthreads();

  if (w < 2) {
    int row = w * 64 + lane;  // 0..127
    float M = sh.mg.m[0][row];
#pragma unroll
    for (int q = 1; q < 16; ++q) M = fmaxf(M, sh.mg.m[q][row]);
    float L = 0.0f;
#pragma unroll
    for (int q = 0; q < 16; ++q)
      L += sh.mg.l[q][row] * wexp2(sh.mg.m[q][row] - M);
    float pw = rowb[row].w;
    float res = pw + neg_eps_ln2 * (M + log2f(L)) + eps_logM;
    float invc = -neg_eps_ln2;
    int idx = (mat * NB + b) * NPTS + rowbase + row;
    am0[idx] = M * invc;
    am1[idx] = (M + log2f(L)) * invc;
    pot_out[idx] = 0.5f * (0.0f + res);
  }
}

// ---------------------------------------------------------------------------
// Deferred fixed-reference sweep (R12 structure; R14 validated the math).
// 512 blocks x 1024 thr; block=(mat(2b), b(3b), rg(3b): 256-row grp,
// cg(1b): 1024-col half). Staging (512 thr): decode h_k = 0.5*(h_{k-1} +
// (pw - lse_{k-1} + elM_prev)) from sweep k-1's L halves (associative sums —
// col-split safe); rg==0 blocks persist pot/amax. Rows: R=4 rows/thread,
// 16 waves = 64-col chunks -> 2048 ds_read_b128/CU. Writes this half's
// partial row sums to LpOut.
// ---------------------------------------------------------------------------
template <bool DECODE>
__global__ __launch_bounds__(1024, 8) void emd_sweep_ref(
    const float4* __restrict__ x4, const float4* __restrict__ y4,
    const float* __restrict__ pot_in, float* __restrict__ pot_out,
    const float* __restrict__ amRows,   // R_{k-1}, rows reference
    const float* __restrict__ amDec,    // R_{k-2}, decode reference
    float* __restrict__ amWr,           // R_k write slot
    const float* __restrict__ LpIn,     // L parts of sweep k-1
    float* __restrict__ LpOut,          // L parts of sweep k
    float c, float invc_prev, float elM_prev) {
  __shared__ union {
    struct { float4 A[512]; float4 B[512]; } cp;   // 16 KB (this cg-half)
    float lbuf[16][256];                           // 16 KB (merge)
  } sh;

  int blk = blockIdx.x;            // 0..511
  int mat = blk >> 7;
  int b = (blk >> 4) & 7;
  int rg = (blk >> 1) & 7;         // 256-row group
  int cg = blk & 1;                // 1024-col half
  int tid = threadIdx.x;
  int lane = tid & 63;
  int w = tid >> 6;                // 0..15

  const float4* rowp = (mat & 1) ? y4 : x4;
  const float4* colp = (mat == 0 || mat == 3) ? y4 : x4;
  int hidx = (mat < 2) ? (mat ^ 1) : mat;
  int hbase = (hidx * NB + b) * NPTS;
  const float4* colb = colp + b * NPTS;

  // ---- staging: decode h, build packed colpack for this 1024-col half ----
  if (tid < 512) {
    int jg = cg * 1024 + 2 * tid;
    float4 q0 = colb[jg];
    float4 q1 = colb[jg + 1];
    float2 hv = *(const float2*)(pot_in + hbase + jg);
    float h0 = hv.x, h1 = hv.y;
    if (DECODE) {
      float2 lpa = *(const float2*)(LpIn + 2 * hbase + jg);
      float2 lpb = *(const float2*)(LpIn + 2 * hbase + NPTS + jg);
      float2 rd = *(const float2*)(amDec + hbase + jg);
      float lse0 = fmaf(log2f(lpa.x + lpb.x), invc_prev, rd.x);
      float lse1 = fmaf(log2f(lpa.y + lpb.y), invc_prev, rd.y);
      float res0 = q0.w - lse0 + elM_prev;
      float res1 = q1.w - lse1 + elM_prev;
      h0 = 0.5f * (h0 + res0);
      h1 = 0.5f * (h1 + res1);
      if (rg == 0) *(float2*)(amWr + hbase + jg) = make_float2(lse0, lse1);
    }
    if (rg == 0) *(float2*)(pot_out + hbase + jg) = make_float2(h0, h1);
    sh.cp.A[tid] = make_float4(q0.x, q1.x, q0.y, q1.y);
    sh.cp.B[tid] = make_float4(q0.z, q1.z, (h0 - q0.w) * c, (h1 - q1.w) * c);
  }
  __syncthreads();

  // ---- rows: R=4 rows/thread, fixed-reference exp accumulate ----
  int rowbase = rg * 256;
  const float4* rowb = rowp + b * NPTS + rowbase;
  const float* amrow = amRows + (mat * NB + b) * NPTS + rowbase;

  v2f xs0[4], xs1[4], xs2[4], mref2[4], acc[4];
#pragma unroll
  for (int r = 0; r < 4; ++r) {
    float4 p = rowb[r * 64 + lane];
    float a0 = p.x * c, a1 = p.y * c, a2 = p.z * c;
    xs0[r] = (v2f){a0, a0};
    xs1[r] = (v2f){a1, a1};
    xs2[r] = (v2f){a2, a2};
    float mr = amrow[r * 64 + lane] * c;
    mref2[r] = (v2f){mr, mr};
    acc[r] = (v2f){0.0f, 0.0f};
  }

  int p0 = w * 32;                 // 32 pairs (64 cols) per wave
  for (int tp = 0; tp < 32; ++tp) {
    float4 A = sh.cp.A[p0 + tp];
    float4 B = sh.cp.B[p0 + tp];
    v2f qx = {A.x, A.y};
    v2f qy = {A.z, A.w};
    v2f qz = {B.x, B.y};
    v2f qw = {B.z, B.w};
#pragma unroll
    for (int r = 0; r < 4; ++r) {
      v2f s2 = fma2(xs0[r], qx, fma2(xs1[r], qy, fma2(xs2[r], qz, qw)));
      v2f d = s2 - mref2[r];
      v2f e;
      e.x = wexp2(d.x);
      e.y = wexp2(d.y);
      acc[r] += e;
    }
  }

  __syncthreads();  // colpack dead; safe to overwrite (union)
#pragma unroll
  for (int r = 0; r < 4; ++r)
    sh.lbuf[w][r * 64 + lane] = acc[r].x + acc[r].y;
  __syncthreads();

  if (w < 4) {
    int row = w * 64 + lane;  // 0..255
    float L = sh.lbuf[0][row];
#pragma unroll
    for (int q = 1; q < 16; ++q) L += sh.lbuf[q][row];
    LpOut[2 * ((mat * NB + b) * NPTS) + cg * NPTS + rowbase + row] = L;
  }
}

// ---------------------------------------------------------------------------
// Finalize: decode the final sweep's L parts into res, signed mean -> out.
// Normalization 1/(NB*NPTS) = 1/16384 (the R12/R13 bug was 1/65536 here).
// ---------------------------------------------------------------------------
__global__ __launch_bounds__(256) void emd_finalize(
    const float4* __restrict__ x4, const float4* __restrict__ y4,
    const float* __restrict__ Lp, const float* __restrict__ amR,
    float* __restrict__ out, float invc_t, float elM_t) {
  int t = blockIdx.x * 256 + threadIdx.x;  // 0..65535
  int mat = t >> 14;
  int b = (t >> 11) & 7;
  int i = t & 2047;
  const float4* pp = (mat & 1) ? y4 : x4;
  float pw = pp[b * NPTS + i].w;
  int base = (mat * NB + b) * NPTS;
  float L = Lp[2 * base + i] + Lp[2 * base + NPTS + i];
  float lse = fmaf(log2f(L), invc_t, amR[base + i]);
  float res = pw - lse + elM_t;
  float sign = (mat < 2) ? 1.0f : -1.0f;
  float val = sign * res * (1.0f / (float)(NB * NPTS));  // 1/16384
#pragma unroll
  for (int off = 32; off; off >>= 1) val += __shfl_xor(val, off);
  if ((threadIdx.x & 63) == 0) atomicAdd(out, val);
}

// ---------------------------------------------------------------------------
extern "C" void kernel_launch(void* const* d_in, const int* in_sizes, int n_in,
                              void* d_out, int out_size, void* d_ws, size_t ws_size,
                              hipStream_t stream) {
  const float* x = (const float*)d_in[0];
  const float* y = (const float*)d_in[1];
  float* out = (float*)d_out;

  char* ws = (char*)d_ws;
  float4* x4 = (float4*)ws;                          // 256 KB
  float4* y4 = (float4*)(ws + 262144);               // 256 KB
  float* pot = (float*)(ws + 524288);                // 2 x 65536 f = 512 KB
  float* am[3];
  am[0] = (float*)(ws + 1048576);                    // 3 x 256 KB
  am[1] = (float*)(ws + 1048576 + 262144);
  am[2] = (float*)(ws + 1048576 + 524288);
  float* Lp[2];
  Lp[0] = (float*)(ws + 1835008);                    // 2 x 512 KB
  Lp[1] = (float*)(ws + 1835008 + 524288);

  emd_init<<<256, 256, 0, stream>>>(x, y, x4, y4, pot, out);

  // eps schedule: s=8.0, *=0.9 while s>0.01; eps=f32(s)^2; append 0.01^2
  float eps_arr[80];
  int ne = 0;
  double s = 8.0;
  while (s > 0.01) {
    float sf = (float)s;
    eps_arr[ne++] = sf * sf;
    s *= 0.9;
  }
  {
    float bf = 0.01f;
    eps_arr[ne++] = bf * bf;
  }

  const double LOG2E = 1.4426950408889634;
  const double LN2 = 0.6931471805599453;
  const double LOG2048 = 7.624618986159398;

  // iteration 0 (boot): pot0 (zeroed) -> pot1 slot, writes am[0], am[1]
  {
    float eps = eps_arr[0];
    float c = (float)(LOG2E / (double)eps);
    float nel = (float)(-(double)eps * LN2);
    float elM = (float)((double)eps * LOG2048);
    emd_sweep_boot<<<512, 1024, 0, stream>>>(x4, y4, pot, pot + 65536,
                                             am[0], am[1], c, nel, elM);
  }

  // sweeps k=1..ne-1 (iterations 1..ne-1) + final extrapolation k=ne
  for (int k = 1; k <= ne; ++k) {
    int ek = (k < ne) ? k : ne - 1;
    float eps = eps_arr[ek];
    float epsp = eps_arr[ek - (k < ne ? 1 : 0)];
    float c = (float)(LOG2E / (double)eps);
    float invc_p = (float)((double)epsp * LN2);
    float elM_p = (float)((double)epsp * LOG2048);
    const float* rowsR = am[(k - 1) % 3];
    const float* decR = am[(k + 1) % 3];  // (k-2) mod 3
    float* wrR = am[k % 3];
    float* potIn = pot + (k % 2) * 65536;
    float* potOut = pot + ((k + 1) % 2) * 65536;
    float* lpIn = Lp[(k - 1) % 2];
    float* lpOut = Lp[k % 2];
    if (k == 1) {
      emd_sweep_ref<false><<<512, 1024, 0, stream>>>(
          x4, y4, potIn, potOut, rowsR, decR, wrR, lpIn, lpOut,
          c, invc_p, elM_p);
    } else {
      emd_sweep_ref<true><<<512, 1024, 0, stream>>>(
          x4, y4, potIn, potOut, rowsR, decR, wrR, lpIn, lpOut,
          c, invc_p, elM_p);
    }
  }

  // finalize: decode L of sweep ne (relative to am[(ne-1)%3]) at eps_t
  {
    float eps_t = eps_arr[ne - 1];
    float invc_t = (float)((double)eps_t * LN2);
    float elM_t = (float)((double)eps_t * LOG2048);
    emd_finalize<<<256, 256, 0, stream>>>(x4, y4, Lp[ne % 2],
                                          am[(ne - 1) % 3], out,
                                          invc_t, elM_t);
  }
}